// Round 2
// baseline (655.483 us; speedup 1.0000x reference)
//
#include <hip/hip_runtime.h>

#define NN 100000
#define EE 1600000
#define C 256
#define OUTC 10
#define NG 64

#define NBK 391            // ceil(NN/256) dst-buckets of 256 nodes
#define CHUNK 2048         // edges per bucket_hist/scatter block (782 blocks)
#define NBLK1 ((EE + CHUNK - 1) / CHUNK)
#define PADSLACK 2048      // per-bucket csrcol slack: 256*7 pad + 7 align < 2048

// agg_pool decomposition: 4 waves/block, each wave owns NODES_PER_GROUP nodes
#define NODES_PER_GROUP 8
#define NODES_PER_BLOCK 32      // 100000 = 32 * 3125 exactly
#define NPASS 4                 // channel slices (64 ch = one 64B line per row)

typedef __bf16 bf16x8 __attribute__((ext_vector_type(8)));
typedef float f32x4 __attribute__((ext_vector_type(4)));
typedef float f32x2 __attribute__((ext_vector_type(2)));

// ---------------- bf16 helpers (RNE) ----------------
__device__ __forceinline__ ushort f2bf(float f) {
    unsigned u = __float_as_uint(f);
    return (ushort)((u + 0x7fffu + ((u >> 16) & 1u)) >> 16);
}
__device__ __forceinline__ bf16x8 as_bf16x8(uint4 v) {
    union { uint4 u; bf16x8 b; } c; c.u = v; return c.b;
}

// fp8 e4m3 encode/decode via HW converts
__device__ __forceinline__ uchar f2fp8(float f) {
    return (uchar)(__builtin_amdgcn_cvt_pk_fp8_f32(f, 0.f, 0, false) & 0xff);
}
__device__ __forceinline__ void acc_fp8x4(float4& s, unsigned v) {
    f32x2 lo = __builtin_amdgcn_cvt_pk_f32_fp8(v, false);
    f32x2 hi = __builtin_amdgcn_cvt_pk_f32_fp8(v, true);
    s.x += lo[0]; s.y += lo[1]; s.z += hi[0]; s.w += hi[1];
}

// ---------------- per-graph node counts: LDS histogram ----------------
__global__ __launch_bounds__(1024) void count_kernel(const int* __restrict__ batch,
                                                     float* __restrict__ cnt) {
    __shared__ int h[NG];
    if (threadIdx.x < NG) h[threadIdx.x] = 0;
    __syncthreads();
    int i = blockIdx.x * blockDim.x + threadIdx.x;
    if (i < NN) atomicAdd(&h[batch[i]], 1);
    __syncthreads();
    if (threadIdx.x < NG) {
        int v = h[threadIdx.x];
        if (v > 0) atomicAdd(&cnt[threadIdx.x], (float)v);
    }
}

// ---------------- bucket histogram (dst>>8), LDS-staged ----------------
__global__ __launch_bounds__(256) void bucket_hist_kernel(const int* __restrict__ ei,
                                                          int* __restrict__ bhist) {
    __shared__ int h[NBK];
    for (int t = threadIdx.x; t < NBK; t += 256) h[t] = 0;
    __syncthreads();
    const int base = blockIdx.x * CHUNK;
    const int end = min(base + CHUNK, EE);
    for (int e = base + threadIdx.x; e < end; e += 256)
        atomicAdd(&h[ei[EE + e] >> 8], 1);
    __syncthreads();
    for (int t = threadIdx.x; t < NBK; t += 256)
        if (h[t]) atomicAdd(&bhist[t], h[t]);
}

// ---------------- parallel exclusive scan of 391 bucket counts ----------------
__global__ __launch_bounds__(512) void bucket_scan_kernel(const int* __restrict__ bhist,
                                                          int* __restrict__ bbase,
                                                          int* __restrict__ bcur) {
    __shared__ int sc[512];
    const int t = threadIdx.x;
    int v = (t < NBK) ? bhist[t] : 0;
    sc[t] = v;
    __syncthreads();
    for (int off = 1; off < 512; off <<= 1) {
        int tmp = (t >= off) ? sc[t - off] : 0;
        __syncthreads();
        sc[t] += tmp;
        __syncthreads();
    }
    int excl = sc[t] - v;
    if (t < NBK) { bbase[t] = excl; bcur[t] = excl; }
    if (t == 0) bbase[NBK] = sc[511];
}

// ---------------- scatter edges into bucket-major packed records ----------------
// record = (dst & 255) << 17 | src
__global__ __launch_bounds__(256) void bucket_scatter_kernel(const int* __restrict__ ei,
                                                             int* __restrict__ bcur,
                                                             unsigned* __restrict__ bmaj) {
    __shared__ int h[NBK];
    for (int t = threadIdx.x; t < NBK; t += 256) h[t] = 0;
    __syncthreads();
    const int base = blockIdx.x * CHUNK;
    const int end = min(base + CHUNK, EE);
    for (int e = base + threadIdx.x; e < end; e += 256)
        atomicAdd(&h[ei[EE + e] >> 8], 1);
    __syncthreads();
    for (int t = threadIdx.x; t < NBK; t += 256) {
        int c = h[t];
        h[t] = c ? atomicAdd(&bcur[t], c) : 0;
    }
    __syncthreads();
    for (int e = base + threadIdx.x; e < end; e += 256) {
        int d = ei[EE + e];
        int s = ei[e];
        int b = d >> 8;
        int p = atomicAdd(&h[b], 1);
        bmaj[p] = (unsigned)s | ((unsigned)(d & 255) << 17);
    }
}

// ---------------- per-bucket: degree, PADDED rowend, dinv, dense csrcol ----------
// Node lists padded to multiple of 8 with sentinel index NN (zero g-row).
// Bucket b's csrcol region starts at align8(bbase[b]) + b*PADSLACK (16B-aligned
// so agg_pool can do int4 index loads).
__global__ __launch_bounds__(256) void bucket_csr_kernel(const unsigned* __restrict__ bmaj,
                                                         const int* __restrict__ bbase,
                                                         int* __restrict__ rowend,
                                                         float* __restrict__ dinv,
                                                         int* __restrict__ csrcol) {
    __shared__ int h[256];
    __shared__ int sc[256];
    __shared__ int cur[256];
    const int b = blockIdx.x;
    const int t = threadIdx.x;
    const int e0 = bbase[b], e1 = bbase[b + 1];
    const int region0 = ((e0 + 7) & ~7) + b * PADSLACK;   // 8-int aligned
    h[t] = 0;
    __syncthreads();
    for (int e = e0 + t; e < e1; e += 256)
        atomicAdd(&h[bmaj[e] >> 17], 1);
    __syncthreads();
    int deg = h[t];
    int pd = (deg + 7) & ~7;               // padded degree
    sc[t] = pd;
    __syncthreads();
    for (int off = 1; off < 256; off <<= 1) {
        int tmp = (t >= off) ? sc[t - off] : 0;
        __syncthreads();
        sc[t] += tmp;
        __syncthreads();
    }
    int pstart = region0 + sc[t] - pd;
    int node = b * 256 + t;
    if (node < NN) {
        rowend[node] = pstart + pd;        // PADDED end
        dinv[node] = rsqrtf((float)deg + 1.0f);
        for (int j = deg; j < pd; j++) csrcol[pstart + j] = NN;   // sentinels
    }
    cur[t] = pstart;
    __syncthreads();
    for (int e = e0 + t; e < e1; e += 256) {
        unsigned v = bmaj[e];
        int p = atomicAdd(&cur[v >> 17], 1);
        csrcol[p] = (int)(v & 0x1FFFFu);
    }
}

// ---------------- W1 -> bf16 fragment-order pack (+ zero sentinel g-row) --------
__global__ __launch_bounds__(256) void w1pack_kernel(const float* __restrict__ W1,
                                                     ushort* __restrict__ w1f,
                                                     unsigned* __restrict__ gz) {
    int t = blockIdx.x * 256 + threadIdx.x;
    if (blockIdx.x == 0 && threadIdx.x < 64) gz[threadIdx.x] = 0;   // g row NN = 0
    int k = t >> 8, n = t & 255;
    int kb = k >> 5, q = (k >> 3) & 3, j = k & 7;
    int nt = n >> 4, ln = (n & 15) + q * 16;
    w1f[(size_t)(((kb * 16 + nt) * 64) + ln) * 8 + j] = f2bf(W1[t]);
}

// ---------------- g = fp8((x @ W1) * dinv[row]) — MFMA, LDS-free ----------------
__global__ __launch_bounds__(256) void gemm_mfma_kernel(const float* __restrict__ x,
                                                        const ushort* __restrict__ w1f,
                                                        const float* __restrict__ dinv,
                                                        uchar* __restrict__ g) {
    const int lane = threadIdx.x & 63;
    const int wid = threadIdx.x >> 6;
    const int wave = blockIdx.x * 4 + wid;
    const int r0 = wave * 32;
    if (r0 >= NN) return;
    const int mrow = lane & 15;
    const int q = lane >> 4;

    f32x4 acc[2][16];
    #pragma unroll
    for (int mt = 0; mt < 2; mt++)
        #pragma unroll
        for (int nt = 0; nt < 16; nt++)
            acc[mt][nt] = (f32x4){0.f, 0.f, 0.f, 0.f};

    const float* xp0 = x + (size_t)(r0 + mrow) * C + q * 8;
    const float* xp1 = xp0 + (size_t)16 * C;
    const ushort* bp = w1f + (size_t)lane * 8;

    #pragma unroll 1
    for (int kb = 0; kb < 8; kb++) {
        const int ko = kb * 32;
        float4 a0lo = *(const float4*)(xp0 + ko);
        float4 a0hi = *(const float4*)(xp0 + ko + 4);
        float4 a1lo = *(const float4*)(xp1 + ko);
        float4 a1hi = *(const float4*)(xp1 + ko + 4);
        bf16x8 a0, a1;
        a0[0] = (__bf16)a0lo.x; a0[1] = (__bf16)a0lo.y;
        a0[2] = (__bf16)a0lo.z; a0[3] = (__bf16)a0lo.w;
        a0[4] = (__bf16)a0hi.x; a0[5] = (__bf16)a0hi.y;
        a0[6] = (__bf16)a0hi.z; a0[7] = (__bf16)a0hi.w;
        a1[0] = (__bf16)a1lo.x; a1[1] = (__bf16)a1lo.y;
        a1[2] = (__bf16)a1lo.z; a1[3] = (__bf16)a1lo.w;
        a1[4] = (__bf16)a1hi.x; a1[5] = (__bf16)a1hi.y;
        a1[6] = (__bf16)a1hi.z; a1[7] = (__bf16)a1hi.w;

        const ushort* bkb = bp + (size_t)kb * 16 * 512;
        #pragma unroll
        for (int nt = 0; nt < 16; nt++) {
            bf16x8 bb = as_bf16x8(*(const uint4*)(bkb + (size_t)nt * 512));
            acc[0][nt] = __builtin_amdgcn_mfma_f32_16x16x32_bf16(a0, bb, acc[0][nt], 0, 0, 0);
            acc[1][nt] = __builtin_amdgcn_mfma_f32_16x16x32_bf16(a1, bb, acc[1][nt], 0, 0, 0);
        }
    }

    #pragma unroll
    for (int mt = 0; mt < 2; mt++) {
        #pragma unroll
        for (int r = 0; r < 4; r++) {
            int row = r0 + mt * 16 + q * 4 + r;
            float dv = dinv[row];
            uchar* gp = g + (size_t)row * C + mrow;
            #pragma unroll
            for (int nt = 0; nt < 16; nt++)
                gp[nt * 16] = f2fp8(acc[mt][nt][r] * dv);
        }
    }
}

// ---------------- aggregate + relu + fused mean-pool (fp8, channel-sliced) ------
// Pass p gathers only bytes [p*64, p*64+64) of each g row (= one 64B cache line)
// so the per-pass gather footprint is 6.4MB instead of 25.6MB -> L2-resident.
// 16 lanes per edge, 4 edges per gather instruction; cross-group shfl reduce.
__global__ __launch_bounds__(256) void agg_pool_kernel(const unsigned* __restrict__ g32,
                                                       const int* __restrict__ rowend,
                                                       const int* __restrict__ csrcol,
                                                       const int* __restrict__ bbase,
                                                       const float* __restrict__ dinv,
                                                       const float* __restrict__ b1,
                                                       const int* __restrict__ batch,
                                                       float* __restrict__ sums,
                                                       const int pass) {
    const int lane = threadIdx.x & 63;
    const int wid = threadIdx.x >> 6;
    const int gq = lane >> 4;              // edge slot within quad: 0..3
    const int cl = lane & 15;              // channel dword within slice: 0..15
    const int cbase = pass * 64 + cl * 4;  // float channel index
    const int nodeA = blockIdx.x * NODES_PER_BLOCK + wid * NODES_PER_GROUP;
    const float4 bv = *(const float4*)&b1[cbase];
    const unsigned* gslice = g32 + (size_t)pass * 16 + cl;   // + i*64 per row

    int rprev;
    if ((nodeA & 255) == 0) {
        int b = nodeA >> 8;
        rprev = ((bbase[b] + 7) & ~7) + b * PADSLACK;   // aligned bucket region start
    } else {
        rprev = rowend[nodeA - 1];
    }

    float4 pool = make_float4(0.f, 0.f, 0.f, 0.f);
    int curb = -1;
    #pragma unroll 1
    for (int i = nodeA; i < nodeA + NODES_PER_GROUP; i++) {
        int r1 = rowend[i];
        int r0 = rprev;
        rprev = r1;
        int bi = batch[i];
        if (bi != curb) {
            if (curb >= 0 && gq == 0) {
                atomicAdd(&sums[curb * C + cbase + 0], pool.x);
                atomicAdd(&sums[curb * C + cbase + 1], pool.y);
                atomicAdd(&sums[curb * C + cbase + 2], pool.z);
                atomicAdd(&sums[curb * C + cbase + 3], pool.w);
            }
            curb = bi;
            pool = make_float4(0.f, 0.f, 0.f, 0.f);
        }
        float4 s = make_float4(0.f, 0.f, 0.f, 0.f);
        if (gq == 0) acc_fp8x4(s, gslice[(size_t)i * 64]);     // self-loop (once)
        #pragma unroll 1
        for (int e = r0; e < r1; e += 8) {
            int4 iv0 = *(const int4*)(csrcol + e);        // 16B aligned (e % 8 == 0)
            int4 iv1 = *(const int4*)(csrcol + e + 4);
            int ia = iv0.x;
            ia = (gq == 1) ? iv0.y : ia;
            ia = (gq == 2) ? iv0.z : ia;
            ia = (gq == 3) ? iv0.w : ia;
            int ib = iv1.x;
            ib = (gq == 1) ? iv1.y : ib;
            ib = (gq == 2) ? iv1.z : ib;
            ib = (gq == 3) ? iv1.w : ib;
            unsigned va = gslice[(size_t)ia * 64];
            unsigned vb = gslice[(size_t)ib * 64];
            acc_fp8x4(s, va);
            acc_fp8x4(s, vb);
        }
        // reduce partial sums across the 4 edge-groups (lanes ^16, ^32)
        s.x += __shfl_xor(s.x, 16); s.y += __shfl_xor(s.y, 16);
        s.z += __shfl_xor(s.z, 16); s.w += __shfl_xor(s.w, 16);
        s.x += __shfl_xor(s.x, 32); s.y += __shfl_xor(s.y, 32);
        s.z += __shfl_xor(s.z, 32); s.w += __shfl_xor(s.w, 32);
        float dv = dinv[i];
        pool.x += fmaxf(fmaf(dv, s.x, bv.x), 0.f);
        pool.y += fmaxf(fmaf(dv, s.y, bv.y), 0.f);
        pool.z += fmaxf(fmaf(dv, s.z, bv.z), 0.f);
        pool.w += fmaxf(fmaf(dv, s.w, bv.w), 0.f);
    }
    if (curb >= 0 && gq == 0) {
        atomicAdd(&sums[curb * C + cbase + 0], pool.x);
        atomicAdd(&sums[curb * C + cbase + 1], pool.y);
        atomicAdd(&sums[curb * C + cbase + 2], pool.z);
        atomicAdd(&sums[curb * C + cbase + 3], pool.w);
    }
}

// ---------------- pooled = sums/cnt; out = pooled @ W2 + b2 ----------------
__global__ __launch_bounds__(256) void final_kernel(const float* __restrict__ sums,
                                                    const float* __restrict__ cnt,
                                                    const float* __restrict__ W2,
                                                    const float* __restrict__ b2,
                                                    float* __restrict__ out) {
    __shared__ float p[C];
    int gi = blockIdx.x;
    float cdiv = fmaxf(cnt[gi], 1.0f);
    p[threadIdx.x] = sums[gi * C + threadIdx.x] / cdiv;
    __syncthreads();
    if (threadIdx.x < OUTC) {
        float acc = b2[threadIdx.x];
        for (int k = 0; k < C; k++) acc += p[k] * W2[k * OUTC + threadIdx.x];
        out[gi * OUTC + threadIdx.x] = acc;
    }
}

extern "C" void kernel_launch(void* const* d_in, const int* in_sizes, int n_in,
                              void* d_out, int out_size, void* d_ws, size_t ws_size,
                              hipStream_t stream) {
    const float* x     = (const float*)d_in[0];
    const int*   ei    = (const int*)d_in[1];
    const int*   batch = (const int*)d_in[2];
    const float* W1    = (const float*)d_in[3];
    const float* b1    = (const float*)d_in[4];
    const float* W2    = (const float*)d_in[5];
    const float* b2    = (const float*)d_in[6];
    float* out = (float*)d_out;

    char* w = (char*)d_ws;
    size_t off = 0;
    auto carve = [&](size_t bytes) {
        void* p = w + off;
        off = (off + bytes + 255) & ~(size_t)255;
        return p;
    };
    uchar*    g        = (uchar*)   carve((size_t)(NN + 1) * C);  // fp8 + sentinel row
    int*      rowend   = (int*)     carve((size_t)NN * 4);
    float*    dinv     = (float*)   carve((size_t)NN * 4);
    int*      csrcol   = (int*)     carve((size_t)(EE + 8 + NBK * PADSLACK) * 4);
    unsigned* bmaj     = (unsigned*)carve((size_t)EE * 4);
    int*      bbase    = (int*)     carve((size_t)(NBK + 1) * 4);
    int*      bcur     = (int*)     carve((size_t)NBK * 4);
    ushort*   w1f      = (ushort*)  carve((size_t)C * C * 2);
    // contiguous zero-init region:
    int*      bhist    = (int*)     carve((size_t)NBK * 4);
    float*    sums     = (float*)   carve((size_t)NG * C * 4);
    float*    cnt      = (float*)   carve((size_t)NG * 4);
    size_t zero_bytes = (size_t)((char*)cnt + (size_t)NG * 4 - (char*)bhist);

    hipMemsetAsync(bhist, 0, zero_bytes, stream);

    bucket_hist_kernel<<<NBLK1, 256, 0, stream>>>(ei, bhist);
    bucket_scan_kernel<<<1, 512, 0, stream>>>(bhist, bbase, bcur);
    bucket_scatter_kernel<<<NBLK1, 256, 0, stream>>>(ei, bcur, bmaj);
    bucket_csr_kernel<<<NBK, 256, 0, stream>>>(bmaj, bbase, rowend, dinv, csrcol);
    count_kernel<<<(NN + 1023) / 1024, 1024, 0, stream>>>(batch, cnt);
    w1pack_kernel<<<C * C / 256, 256, 0, stream>>>(W1, w1f, (unsigned*)(g + (size_t)NN * C));
    gemm_mfma_kernel<<<(NN / 32 + 3) / 4, 256, 0, stream>>>(x, w1f, dinv, g);
    for (int pass = 0; pass < NPASS; pass++)
        agg_pool_kernel<<<NN / NODES_PER_BLOCK, 256, 0, stream>>>(
            (const unsigned*)g, rowend, csrcol, bbase, dinv, b1, batch, sums, pass);
    final_kernel<<<NG, 256, 0, stream>>>(sums, cnt, W2, b2, out);
}

// Round 3
// 424.581 us; speedup vs baseline: 1.5438x; 1.5438x over previous
//
#include <hip/hip_runtime.h>

#define NN 100000
#define EE 1600000
#define C 256
#define OUTC 10
#define NG 64

#define NBK 391            // ceil(NN/256) dst-buckets of 256 nodes
#define CHUNK 2048         // edges per bucket_hist/scatter block (782 blocks)
#define NBLK1 ((EE + CHUNK - 1) / CHUNK)
#define PADSLACK 2048      // per-bucket csrcol slack: 256*7 pad + 7 align < 2048

// agg_pool decomposition: 4 waves/block, each wave owns NODES_PER_GROUP nodes
#define NODES_PER_GROUP 8
#define NODES_PER_BLOCK 32      // 100000 = 32 * 3125 exactly

typedef __bf16 bf16x8 __attribute__((ext_vector_type(8)));
typedef float f32x4 __attribute__((ext_vector_type(4)));
typedef float f32x2 __attribute__((ext_vector_type(2)));

// ---------------- bf16 helpers (RNE) ----------------
__device__ __forceinline__ ushort f2bf(float f) {
    unsigned u = __float_as_uint(f);
    return (ushort)((u + 0x7fffu + ((u >> 16) & 1u)) >> 16);
}
__device__ __forceinline__ bf16x8 as_bf16x8(uint4 v) {
    union { uint4 u; bf16x8 b; } c; c.u = v; return c.b;
}

// fp8 e4m3 encode/decode via HW converts
__device__ __forceinline__ uchar f2fp8(float f) {
    return (uchar)(__builtin_amdgcn_cvt_pk_fp8_f32(f, 0.f, 0, false) & 0xff);
}
__device__ __forceinline__ void acc_fp8x4(float4& s, unsigned v) {
    f32x2 lo = __builtin_amdgcn_cvt_pk_f32_fp8(v, false);
    f32x2 hi = __builtin_amdgcn_cvt_pk_f32_fp8(v, true);
    s.x += lo[0]; s.y += lo[1]; s.z += hi[0]; s.w += hi[1];
}

// ---------------- per-graph node counts: LDS histogram ----------------
__global__ __launch_bounds__(1024) void count_kernel(const int* __restrict__ batch,
                                                     float* __restrict__ cnt) {
    __shared__ int h[NG];
    if (threadIdx.x < NG) h[threadIdx.x] = 0;
    __syncthreads();
    int i = blockIdx.x * blockDim.x + threadIdx.x;
    if (i < NN) atomicAdd(&h[batch[i]], 1);
    __syncthreads();
    if (threadIdx.x < NG) {
        int v = h[threadIdx.x];
        if (v > 0) atomicAdd(&cnt[threadIdx.x], (float)v);
    }
}

// ---------------- bucket histogram (dst>>8), LDS-staged ----------------
__global__ __launch_bounds__(256) void bucket_hist_kernel(const int* __restrict__ ei,
                                                          int* __restrict__ bhist) {
    __shared__ int h[NBK];
    for (int t = threadIdx.x; t < NBK; t += 256) h[t] = 0;
    __syncthreads();
    const int base = blockIdx.x * CHUNK;
    const int end = min(base + CHUNK, EE);
    for (int e = base + threadIdx.x; e < end; e += 256)
        atomicAdd(&h[ei[EE + e] >> 8], 1);
    __syncthreads();
    for (int t = threadIdx.x; t < NBK; t += 256)
        if (h[t]) atomicAdd(&bhist[t], h[t]);
}

// ---------------- parallel exclusive scan of 391 bucket counts ----------------
__global__ __launch_bounds__(512) void bucket_scan_kernel(const int* __restrict__ bhist,
                                                          int* __restrict__ bbase,
                                                          int* __restrict__ bcur) {
    __shared__ int sc[512];
    const int t = threadIdx.x;
    int v = (t < NBK) ? bhist[t] : 0;
    sc[t] = v;
    __syncthreads();
    for (int off = 1; off < 512; off <<= 1) {
        int tmp = (t >= off) ? sc[t - off] : 0;
        __syncthreads();
        sc[t] += tmp;
        __syncthreads();
    }
    int excl = sc[t] - v;
    if (t < NBK) { bbase[t] = excl; bcur[t] = excl; }
    if (t == 0) bbase[NBK] = sc[511];
}

// ---------------- scatter edges into bucket-major packed records ----------------
// record = (dst & 255) << 17 | src
__global__ __launch_bounds__(256) void bucket_scatter_kernel(const int* __restrict__ ei,
                                                             int* __restrict__ bcur,
                                                             unsigned* __restrict__ bmaj) {
    __shared__ int h[NBK];
    for (int t = threadIdx.x; t < NBK; t += 256) h[t] = 0;
    __syncthreads();
    const int base = blockIdx.x * CHUNK;
    const int end = min(base + CHUNK, EE);
    for (int e = base + threadIdx.x; e < end; e += 256)
        atomicAdd(&h[ei[EE + e] >> 8], 1);
    __syncthreads();
    for (int t = threadIdx.x; t < NBK; t += 256) {
        int c = h[t];
        h[t] = c ? atomicAdd(&bcur[t], c) : 0;
    }
    __syncthreads();
    for (int e = base + threadIdx.x; e < end; e += 256) {
        int d = ei[EE + e];
        int s = ei[e];
        int b = d >> 8;
        int p = atomicAdd(&h[b], 1);
        bmaj[p] = (unsigned)s | ((unsigned)(d & 255) << 17);
    }
}

// ---------------- per-bucket: degree, PADDED rowend, dinv, dense csrcol ----------
// Node lists padded to multiple of 8 with sentinel index NN (zero g-row).
// Bucket b's csrcol region starts at align8(bbase[b]) + b*PADSLACK (16B-aligned
// so agg_pool can do int4 index loads).
__global__ __launch_bounds__(256) void bucket_csr_kernel(const unsigned* __restrict__ bmaj,
                                                         const int* __restrict__ bbase,
                                                         int* __restrict__ rowend,
                                                         float* __restrict__ dinv,
                                                         int* __restrict__ csrcol) {
    __shared__ int h[256];
    __shared__ int sc[256];
    __shared__ int cur[256];
    const int b = blockIdx.x;
    const int t = threadIdx.x;
    const int e0 = bbase[b], e1 = bbase[b + 1];
    const int region0 = ((e0 + 7) & ~7) + b * PADSLACK;   // 8-int aligned
    h[t] = 0;
    __syncthreads();
    for (int e = e0 + t; e < e1; e += 256)
        atomicAdd(&h[bmaj[e] >> 17], 1);
    __syncthreads();
    int deg = h[t];
    int pd = (deg + 7) & ~7;               // padded degree
    sc[t] = pd;
    __syncthreads();
    for (int off = 1; off < 256; off <<= 1) {
        int tmp = (t >= off) ? sc[t - off] : 0;
        __syncthreads();
        sc[t] += tmp;
        __syncthreads();
    }
    int pstart = region0 + sc[t] - pd;
    int node = b * 256 + t;
    if (node < NN) {
        rowend[node] = pstart + pd;        // PADDED end
        dinv[node] = rsqrtf((float)deg + 1.0f);
        for (int j = deg; j < pd; j++) csrcol[pstart + j] = NN;   // sentinels
    }
    cur[t] = pstart;
    __syncthreads();
    for (int e = e0 + t; e < e1; e += 256) {
        unsigned v = bmaj[e];
        int p = atomicAdd(&cur[v >> 17], 1);
        csrcol[p] = (int)(v & 0x1FFFFu);
    }
}

// ---------------- W1 -> bf16 fragment-order pack (+ zero sentinel g-row) --------
__global__ __launch_bounds__(256) void w1pack_kernel(const float* __restrict__ W1,
                                                     ushort* __restrict__ w1f,
                                                     unsigned* __restrict__ gz) {
    int t = blockIdx.x * 256 + threadIdx.x;
    if (blockIdx.x == 0 && threadIdx.x < 64) gz[threadIdx.x] = 0;   // g row NN = 0
    int k = t >> 8, n = t & 255;
    int kb = k >> 5, q = (k >> 3) & 3, j = k & 7;
    int nt = n >> 4, ln = (n & 15) + q * 16;
    w1f[(size_t)(((kb * 16 + nt) * 64) + ln) * 8 + j] = f2bf(W1[t]);
}

// ---------------- g = fp8((x @ W1) * dinv[row]) — MFMA, LDS-free ----------------
__global__ __launch_bounds__(256) void gemm_mfma_kernel(const float* __restrict__ x,
                                                        const ushort* __restrict__ w1f,
                                                        const float* __restrict__ dinv,
                                                        uchar* __restrict__ g) {
    const int lane = threadIdx.x & 63;
    const int wid = threadIdx.x >> 6;
    const int wave = blockIdx.x * 4 + wid;
    const int r0 = wave * 32;
    if (r0 >= NN) return;
    const int mrow = lane & 15;
    const int q = lane >> 4;

    f32x4 acc[2][16];
    #pragma unroll
    for (int mt = 0; mt < 2; mt++)
        #pragma unroll
        for (int nt = 0; nt < 16; nt++)
            acc[mt][nt] = (f32x4){0.f, 0.f, 0.f, 0.f};

    const float* xp0 = x + (size_t)(r0 + mrow) * C + q * 8;
    const float* xp1 = xp0 + (size_t)16 * C;
    const ushort* bp = w1f + (size_t)lane * 8;

    #pragma unroll 1
    for (int kb = 0; kb < 8; kb++) {
        const int ko = kb * 32;
        float4 a0lo = *(const float4*)(xp0 + ko);
        float4 a0hi = *(const float4*)(xp0 + ko + 4);
        float4 a1lo = *(const float4*)(xp1 + ko);
        float4 a1hi = *(const float4*)(xp1 + ko + 4);
        bf16x8 a0, a1;
        a0[0] = (__bf16)a0lo.x; a0[1] = (__bf16)a0lo.y;
        a0[2] = (__bf16)a0lo.z; a0[3] = (__bf16)a0lo.w;
        a0[4] = (__bf16)a0hi.x; a0[5] = (__bf16)a0hi.y;
        a0[6] = (__bf16)a0hi.z; a0[7] = (__bf16)a0hi.w;
        a1[0] = (__bf16)a1lo.x; a1[1] = (__bf16)a1lo.y;
        a1[2] = (__bf16)a1lo.z; a1[3] = (__bf16)a1lo.w;
        a1[4] = (__bf16)a1hi.x; a1[5] = (__bf16)a1hi.y;
        a1[6] = (__bf16)a1hi.z; a1[7] = (__bf16)a1hi.w;

        const ushort* bkb = bp + (size_t)kb * 16 * 512;
        #pragma unroll
        for (int nt = 0; nt < 16; nt++) {
            bf16x8 bb = as_bf16x8(*(const uint4*)(bkb + (size_t)nt * 512));
            acc[0][nt] = __builtin_amdgcn_mfma_f32_16x16x32_bf16(a0, bb, acc[0][nt], 0, 0, 0);
            acc[1][nt] = __builtin_amdgcn_mfma_f32_16x16x32_bf16(a1, bb, acc[1][nt], 0, 0, 0);
        }
    }

    #pragma unroll
    for (int mt = 0; mt < 2; mt++) {
        #pragma unroll
        for (int r = 0; r < 4; r++) {
            int row = r0 + mt * 16 + q * 4 + r;
            float dv = dinv[row];
            uchar* gp = g + (size_t)row * C + mrow;
            #pragma unroll
            for (int nt = 0; nt < 16; nt++)
                gp[nt * 16] = f2fp8(acc[mt][nt][r] * dv);
        }
    }
}

// ---------------- aggregate + relu + fused mean-pool (fp8, padded lists) --------
// Full-row gather (64 lanes x 4B = 256B per edge). Two named 8-gather batches
// (A/B) ping-pong so 16 row-gathers stay in flight per wave; launch_bounds
// (256,4) caps VGPR at 128 so the compiler does NOT serialize loads to fit 32.
#define LOADB(p, E) do {                                                     \
    int4 _i0 = *(const int4*)(csrcol + (E));                                 \
    int4 _i1 = *(const int4*)(csrcol + (E) + 4);                             \
    p##0 = gp[(size_t)_i0.x * 64];                                           \
    p##1 = gp[(size_t)_i0.y * 64];                                           \
    p##2 = gp[(size_t)_i0.z * 64];                                           \
    p##3 = gp[(size_t)_i0.w * 64];                                           \
    p##4 = gp[(size_t)_i1.x * 64];                                           \
    p##5 = gp[(size_t)_i1.y * 64];                                           \
    p##6 = gp[(size_t)_i1.z * 64];                                           \
    p##7 = gp[(size_t)_i1.w * 64];                                           \
} while (0)

#define ACCB(p) do {                                                         \
    acc_fp8x4(s, p##0); acc_fp8x4(s, p##1); acc_fp8x4(s, p##2);              \
    acc_fp8x4(s, p##3); acc_fp8x4(s, p##4); acc_fp8x4(s, p##5);              \
    acc_fp8x4(s, p##6); acc_fp8x4(s, p##7);                                  \
} while (0)

__global__ __launch_bounds__(256, 4) void agg_pool_kernel(const unsigned* __restrict__ g32,
                                                          const int* __restrict__ rowend,
                                                          const int* __restrict__ csrcol,
                                                          const int* __restrict__ bbase,
                                                          const float* __restrict__ dinv,
                                                          const float* __restrict__ b1,
                                                          const int* __restrict__ batch,
                                                          float* __restrict__ sums) {
    const int lane = threadIdx.x & 63;
    const int wid = threadIdx.x >> 6;
    const int c4 = lane * 4;
    const int nodeA = blockIdx.x * NODES_PER_BLOCK + wid * NODES_PER_GROUP;
    const float4 bv = *(const float4*)&b1[c4];
    const unsigned* gp = g32 + lane;

    int rprev;
    if ((nodeA & 255) == 0) {
        int b = nodeA >> 8;
        rprev = ((bbase[b] + 7) & ~7) + b * PADSLACK;   // aligned bucket region start
    } else {
        rprev = rowend[nodeA - 1];
    }

    float4 pool = make_float4(0.f, 0.f, 0.f, 0.f);
    int curb = -1;
    #pragma unroll 1
    for (int i = nodeA; i < nodeA + NODES_PER_GROUP; i++) {
        int r1 = rowend[i];
        int r0 = rprev;
        rprev = r1;
        int bi = batch[i];
        if (bi != curb) {
            if (curb >= 0) {
                atomicAdd(&sums[curb * C + c4 + 0], pool.x);
                atomicAdd(&sums[curb * C + c4 + 1], pool.y);
                atomicAdd(&sums[curb * C + c4 + 2], pool.z);
                atomicAdd(&sums[curb * C + c4 + 3], pool.w);
            }
            curb = bi;
            pool = make_float4(0.f, 0.f, 0.f, 0.f);
        }
        float4 s = make_float4(0.f, 0.f, 0.f, 0.f);
        unsigned vself = gp[(size_t)i * 64];            // self-loop term
        unsigned A0, A1, A2, A3, A4, A5, A6, A7;
        unsigned B0, B1, B2, B3, B4, B5, B6, B7;
        int e = r0;
        if (e < r1) {
            LOADB(A, e); e += 8;
            if (e < r1) {
                LOADB(B, e); e += 8;
                acc_fp8x4(s, vself);
                #pragma unroll 1
                for (;;) {
                    ACCB(A);
                    if (e >= r1) { ACCB(B); break; }
                    LOADB(A, e); e += 8;
                    ACCB(B);
                    if (e >= r1) { ACCB(A); break; }
                    LOADB(B, e); e += 8;
                }
            } else {
                acc_fp8x4(s, vself);
                ACCB(A);
            }
        } else {
            acc_fp8x4(s, vself);
        }
        float dv = dinv[i];
        pool.x += fmaxf(fmaf(dv, s.x, bv.x), 0.f);
        pool.y += fmaxf(fmaf(dv, s.y, bv.y), 0.f);
        pool.z += fmaxf(fmaf(dv, s.z, bv.z), 0.f);
        pool.w += fmaxf(fmaf(dv, s.w, bv.w), 0.f);
    }
    if (curb >= 0) {
        atomicAdd(&sums[curb * C + c4 + 0], pool.x);
        atomicAdd(&sums[curb * C + c4 + 1], pool.y);
        atomicAdd(&sums[curb * C + c4 + 2], pool.z);
        atomicAdd(&sums[curb * C + c4 + 3], pool.w);
    }
}

// ---------------- pooled = sums/cnt; out = pooled @ W2 + b2 ----------------
__global__ __launch_bounds__(256) void final_kernel(const float* __restrict__ sums,
                                                    const float* __restrict__ cnt,
                                                    const float* __restrict__ W2,
                                                    const float* __restrict__ b2,
                                                    float* __restrict__ out) {
    __shared__ float p[C];
    int gi = blockIdx.x;
    float cdiv = fmaxf(cnt[gi], 1.0f);
    p[threadIdx.x] = sums[gi * C + threadIdx.x] / cdiv;
    __syncthreads();
    if (threadIdx.x < OUTC) {
        float acc = b2[threadIdx.x];
        for (int k = 0; k < C; k++) acc += p[k] * W2[k * OUTC + threadIdx.x];
        out[gi * OUTC + threadIdx.x] = acc;
    }
}

extern "C" void kernel_launch(void* const* d_in, const int* in_sizes, int n_in,
                              void* d_out, int out_size, void* d_ws, size_t ws_size,
                              hipStream_t stream) {
    const float* x     = (const float*)d_in[0];
    const int*   ei    = (const int*)d_in[1];
    const int*   batch = (const int*)d_in[2];
    const float* W1    = (const float*)d_in[3];
    const float* b1    = (const float*)d_in[4];
    const float* W2    = (const float*)d_in[5];
    const float* b2    = (const float*)d_in[6];
    float* out = (float*)d_out;

    char* w = (char*)d_ws;
    size_t off = 0;
    auto carve = [&](size_t bytes) {
        void* p = w + off;
        off = (off + bytes + 255) & ~(size_t)255;
        return p;
    };
    uchar*    g        = (uchar*)   carve((size_t)(NN + 1) * C);  // fp8 + sentinel row
    int*      rowend   = (int*)     carve((size_t)NN * 4);
    float*    dinv     = (float*)   carve((size_t)NN * 4);
    int*      csrcol   = (int*)     carve((size_t)(EE + 8 + NBK * PADSLACK) * 4);
    unsigned* bmaj     = (unsigned*)carve((size_t)EE * 4);
    int*      bbase    = (int*)     carve((size_t)(NBK + 1) * 4);
    int*      bcur     = (int*)     carve((size_t)NBK * 4);
    ushort*   w1f      = (ushort*)  carve((size_t)C * C * 2);
    // contiguous zero-init region:
    int*      bhist    = (int*)     carve((size_t)NBK * 4);
    float*    sums     = (float*)   carve((size_t)NG * C * 4);
    float*    cnt      = (float*)   carve((size_t)NG * 4);
    size_t zero_bytes = (size_t)((char*)cnt + (size_t)NG * 4 - (char*)bhist);

    hipMemsetAsync(bhist, 0, zero_bytes, stream);

    bucket_hist_kernel<<<NBLK1, 256, 0, stream>>>(ei, bhist);
    bucket_scan_kernel<<<1, 512, 0, stream>>>(bhist, bbase, bcur);
    bucket_scatter_kernel<<<NBLK1, 256, 0, stream>>>(ei, bcur, bmaj);
    bucket_csr_kernel<<<NBK, 256, 0, stream>>>(bmaj, bbase, rowend, dinv, csrcol);
    count_kernel<<<(NN + 1023) / 1024, 1024, 0, stream>>>(batch, cnt);
    w1pack_kernel<<<C * C / 256, 256, 0, stream>>>(W1, w1f, (unsigned*)(g + (size_t)NN * C));
    gemm_mfma_kernel<<<(NN / 32 + 3) / 4, 256, 0, stream>>>(x, w1f, dinv, g);
    agg_pool_kernel<<<NN / NODES_PER_BLOCK, 256, 0, stream>>>(
        (const unsigned*)g, rowend, csrcol, bbase, dinv, b1, batch, sums);
    final_kernel<<<NG, 256, 0, stream>>>(sums, cnt, W2, b2, out);
}